// Round 6
// baseline (764.354 us; speedup 1.0000x reference)
//
#include <hip/hip_runtime.h>
#include <math.h>

typedef _Float16 f16;
typedef _Float16 f16x8 __attribute__((ext_vector_type(8)));
typedef _Float16 f16x4 __attribute__((ext_vector_type(4)));
typedef float f32x4v __attribute__((ext_vector_type(4)));

#define Bb 8
#define Ss 2048
#define Ee 1024
#define BSr (Bb*Ss)

// ---------------------------------------------------------------- helpers
__device__ __forceinline__ void gll16(const void* gp, void* lp) {
    // async global->LDS, 16B per lane, LDS dest = wave-uniform base + lane*16
    __builtin_amdgcn_global_load_lds(
        (const __attribute__((address_space(1))) unsigned int*)gp,
        (__attribute__((address_space(3))) unsigned int*)lp,
        16, 0, 0);
}

#define MFMA16(a, b, c) __builtin_amdgcn_mfma_f32_16x16x32_f16((a), (b), (c), 0, 0, 0)
#define SBAR() asm volatile("s_barrier" ::: "memory")
#define WAIT_LGKM0() do { asm volatile("s_waitcnt lgkmcnt(0)" ::: "memory"); __builtin_amdgcn_sched_barrier(0); } while (0)

// ================================================================ split kernels
__global__ __launch_bounds__(256)
void split_weights(const float* __restrict__ Wq, const float* __restrict__ Wk,
                   const float* __restrict__ Wv,
                   f16* __restrict__ Wqh, f16* __restrict__ Wql,
                   f16* __restrict__ Wkh, f16* __restrict__ Wkl,
                   f16* __restrict__ Wvh)
{
    const int i = (blockIdx.x * 256 + threadIdx.x) * 4;
    float4 q = *(const float4*)&Wq[i];
    float4 k = *(const float4*)&Wk[i];
    float4 v = *(const float4*)&Wv[i];
    f16x4 qh4, ql4, kh4, kl4, vh4;
#define SPL(val, h4, l4, idx) { f16 hh = (f16)(val); h4[idx] = hh; l4[idx] = (f16)((val) - (float)hh); }
    SPL(q.x, qh4, ql4, 0) SPL(q.y, qh4, ql4, 1) SPL(q.z, qh4, ql4, 2) SPL(q.w, qh4, ql4, 3)
    SPL(k.x, kh4, kl4, 0) SPL(k.y, kh4, kl4, 1) SPL(k.z, kh4, kl4, 2) SPL(k.w, kh4, kl4, 3)
#undef SPL
    vh4[0] = (f16)v.x; vh4[1] = (f16)v.y; vh4[2] = (f16)v.z; vh4[3] = (f16)v.w;
    *(f16x4*)&Wqh[i] = qh4; *(f16x4*)&Wql[i] = ql4;
    *(f16x4*)&Wkh[i] = kh4; *(f16x4*)&Wkl[i] = kl4;
    *(f16x4*)&Wvh[i] = vh4;
}

__global__ __launch_bounds__(256)
void split_x(const float* __restrict__ x, f16* __restrict__ xh, f16* __restrict__ xl)
{
    const int i = (blockIdx.x * 256 + threadIdx.x) * 4;
    float4 v = *(const float4*)&x[i];
    f16x4 h4, l4;
#define SPL(val, idx) { f16 hh = (f16)(val); h4[idx] = hh; l4[idx] = (f16)((val) - (float)hh); }
    SPL(v.x, 0) SPL(v.y, 1) SPL(v.z, 2) SPL(v.w, 3)
#undef SPL
    *(f16x4*)&xh[i] = h4;
    *(f16x4*)&xl[i] = l4;
}

// ================================================================ 8-phase 256x256 K-loop core
// BM=BN=256, BK=64, 512 threads = 8 waves. LDS: fragment-ordered 1024B
// subtiles. Wave w stages row/col-groups w and w+8.
// Staging schedule (round-6): ALL 4 A-glls for tile t+1 issued in ph0 of
// tile t; ALL 4 B-glls in ph1. Issue order per tile: A0 A0' A1 A1' B0 B0'
// B1 B1'. Waits (per-wave counts; wait-then-SBAR gives cross-wave vis):
//   end-ph1: vmcnt(8)  -> drains prev tile's B1,B1' => curr ks1 ready
//            (issue->wait distance ~4-5 phases; was 2 in round-5 => stalls)
//   end-ph3: vmcnt(2)  -> leaves B1,B1' => next ks0 (A+B) ready
//   last tile: vmcnt(0) at end-ph1; no wait at end-ph3.
__device__ __forceinline__ void kloop8(
    const f16* Ap0, const f16* Ap1, const f16* Ap2,
    const f16* Bp0, const f16* Bp1, const f16* Bp2,
    const int npass, f16* As, f16* Bs,
    f32x4v acc[8][4], const int w, const int lane)
{
    const int wr = w >> 2, wc = w & 3;
    // fragment-order per-lane source: wave's row-group base + in-group row + k-chunk
    const int srcoff = (w * 16 + (lane & 15)) * Ee + (lane >> 4) * 8;
    const int lread = lane * 8;                             // 16B per lane
    const int nvt = npass << 4;                             // 16 K-tiles per pass

    // prologue: tile 0 (pass 0) fully into buf 0, drain once
    {
        const f16* gA = Ap0 + srcoff;
        const f16* gB = Bp0 + srcoff;
        f16* lA = As + w * 512;
        f16* lB = Bs + w * 512;
        gll16(gA,                       lA);              // ks0, group w
        gll16(gA + (size_t)8 * 16 * Ee, lA + 8 * 512);    // ks0, group w+8
        gll16(gA + 32,                  lA + 16 * 512);   // ks1, group w
        gll16(gA + 32 + (size_t)8 * 16 * Ee, lA + 24 * 512);
        gll16(gB,                       lB);
        gll16(gB + (size_t)8 * 16 * Ee, lB + 8 * 512);
        gll16(gB + 32,                  lB + 16 * 512);
        gll16(gB + 32 + (size_t)8 * 16 * Ee, lB + 24 * 512);
    }
    asm volatile("s_waitcnt vmcnt(0)" ::: "memory");
    SBAR();

    for (int vt = 0; vt < nvt; ++vt) {
        const int buf = vt & 1;
        const bool more = (vt + 1 < nvt);
        const int tn = (vt + 1) & 15;
        const int pn = (vt + 1) >> 4;
        const f16* An = (pn == 0) ? Ap0 : ((pn == 1) ? Ap1 : Ap2);
        const f16* Bn = (pn == 0) ? Bp0 : ((pn == 1) ? Bp1 : Bp2);
        const f16* An_g = An + tn * 64 + srcoff;
        const f16* Bn_g = Bn + tn * 64 + srcoff;
        f16* As_wr = As + (buf ^ 1) * 16384 + w * 512;
        f16* Bs_wr = Bs + (buf ^ 1) * 16384 + w * 512;
        const f16* As_rd = As + buf * 16384;
        const f16* Bs_rd = Bs + buf * 16384;

        f16x8 fa[8], fb0, fb1;

        // ---------------- ph0: ks0, N-frags 0,1  (+ all 4 A-glls for t+1)
        #pragma unroll
        for (int i = 0; i < 8; ++i)
            fa[i] = *(const f16x8*)(As_rd + (wr * 8 + i) * 512 + lread);
        fb0 = *(const f16x8*)(Bs_rd + (wc * 4 + 0) * 512 + lread);
        fb1 = *(const f16x8*)(Bs_rd + (wc * 4 + 1) * 512 + lread);
        if (more) {
            gll16(An_g,                            As_wr);             // A0
            gll16(An_g + (size_t)8 * 16 * Ee,      As_wr + 8 * 512);   // A0'
            gll16(An_g + 32,                       As_wr + 16 * 512);  // A1
            gll16(An_g + 32 + (size_t)8 * 16 * Ee, As_wr + 24 * 512);  // A1'
        }
        SBAR();
        WAIT_LGKM0();
        __builtin_amdgcn_s_setprio(1);
        #pragma unroll
        for (int i = 0; i < 8; ++i) {
            acc[i][0] = MFMA16(fa[i], fb0, acc[i][0]);
            acc[i][1] = MFMA16(fa[i], fb1, acc[i][1]);
        }
        __builtin_amdgcn_s_setprio(0);
        SBAR();

        // ---------------- ph1: ks0, N-frags 2,3  (+ all 4 B-glls for t+1)
        fb0 = *(const f16x8*)(Bs_rd + (wc * 4 + 2) * 512 + lread);
        fb1 = *(const f16x8*)(Bs_rd + (wc * 4 + 3) * 512 + lread);
        if (more) {
            gll16(Bn_g,                            Bs_wr);             // B0
            gll16(Bn_g + (size_t)8 * 16 * Ee,      Bs_wr + 8 * 512);   // B0'
            gll16(Bn_g + 32,                       Bs_wr + 16 * 512);  // B1
            gll16(Bn_g + 32 + (size_t)8 * 16 * Ee, Bs_wr + 24 * 512);  // B1'
        }
        SBAR();
        WAIT_LGKM0();
        __builtin_amdgcn_s_setprio(1);
        #pragma unroll
        for (int i = 0; i < 8; ++i) {
            acc[i][2] = MFMA16(fa[i], fb0, acc[i][2]);
            acc[i][3] = MFMA16(fa[i], fb1, acc[i][3]);
        }
        __builtin_amdgcn_s_setprio(0);
        // curr ks1 ready: drain prev tile's last 2 (B1,B1'); last tile: full
        if (more) asm volatile("s_waitcnt vmcnt(8)" ::: "memory");
        else      asm volatile("s_waitcnt vmcnt(0)" ::: "memory");
        SBAR();

        // ---------------- ph2: ks1, N-frags 0,1
        #pragma unroll
        for (int i = 0; i < 8; ++i)
            fa[i] = *(const f16x8*)(As_rd + (16 + wr * 8 + i) * 512 + lread);
        fb0 = *(const f16x8*)(Bs_rd + (16 + wc * 4 + 0) * 512 + lread);
        fb1 = *(const f16x8*)(Bs_rd + (16 + wc * 4 + 1) * 512 + lread);
        SBAR();
        WAIT_LGKM0();
        __builtin_amdgcn_s_setprio(1);
        #pragma unroll
        for (int i = 0; i < 8; ++i) {
            acc[i][0] = MFMA16(fa[i], fb0, acc[i][0]);
            acc[i][1] = MFMA16(fa[i], fb1, acc[i][1]);
        }
        __builtin_amdgcn_s_setprio(0);
        SBAR();

        // ---------------- ph3: ks1, N-frags 2,3
        fb0 = *(const f16x8*)(Bs_rd + (16 + wc * 4 + 2) * 512 + lread);
        fb1 = *(const f16x8*)(Bs_rd + (16 + wc * 4 + 3) * 512 + lread);
        SBAR();
        WAIT_LGKM0();
        __builtin_amdgcn_s_setprio(1);
        #pragma unroll
        for (int i = 0; i < 8; ++i) {
            acc[i][2] = MFMA16(fa[i], fb0, acc[i][2]);
            acc[i][3] = MFMA16(fa[i], fb1, acc[i][3]);
        }
        __builtin_amdgcn_s_setprio(0);
        // next ks0 (A+B) ready: leave only B1,B1' outstanding
        if (more) asm volatile("s_waitcnt vmcnt(2)" ::: "memory");
        SBAR();
    }
}

// ================================================================ Kernel B: projection (8-phase)
// grid 768 = 12 (4 ncol x 3 z) x 64 row-tiles, XCD-swizzled.
__global__ __launch_bounds__(512, 2)
void proj8(const f16* __restrict__ xh, const f16* __restrict__ xl,
           const f16* __restrict__ Wqh, const f16* __restrict__ Wql,
           const f16* __restrict__ Wkh, const f16* __restrict__ Wkl,
           const f16* __restrict__ Wvh,
           const float* __restrict__ bq, const float* __restrict__ bk,
           const float* __restrict__ bv,
           f16* __restrict__ qh, f16* __restrict__ ql,
           f16* __restrict__ kh, f16* __restrict__ kl,
           f16* __restrict__ vT)
{
    __shared__ f16 As[32768];   // 64 KB: 2 buf x 32 subtiles x 1024B
    __shared__ f16 Bs[32768];

    const int lin = blockIdx.x;
    const int l = (lin & 7) * 96 + (lin >> 3);   // 768/8 = 96
    const int bx12 = l % 12;
    const int by = l / 12;
    const int z = bx12 >> 2;
    const int col0 = (bx12 & 3) * 256;
    const int row0 = by * 256;

    const f16* Wh = (z == 0) ? Wqh : ((z == 1) ? Wkh : Wvh);
    const f16* Wl = (z == 0) ? Wql : Wkl;
    const float* bias = (z == 0) ? bq : ((z == 1) ? bk : bv);
    const int npass = (z == 2) ? 1 : 3;

    const int t = threadIdx.x;
    const int lane = t & 63;
    const int w = t >> 6;
    const int wr = w >> 2, wc = w & 3;

    const f16* Axh = xh + (size_t)row0 * Ee;
    const f16* Axl = xl + (size_t)row0 * Ee;
    const f16* Bwh = Wh + (size_t)col0 * Ee;
    const f16* Bwl = Wl + (size_t)col0 * Ee;

    f32x4v acc[8][4];
    #pragma unroll
    for (int i = 0; i < 8; ++i)
        #pragma unroll
        for (int j = 0; j < 4; ++j) acc[i][j] = (f32x4v)0.f;

    // passes: (xh,Wh), (xh,Wl), (xl,Wh)  [z==2: (xh,Wvh) only]
    kloop8(Axh, Axh, Axl, Bwh, Bwl, Bwh, npass, As, Bs, acc, w, lane);

    if (z < 2) {
        f16* __restrict__ oh = (z == 0) ? qh : kh;
        f16* __restrict__ ol = (z == 0) ? ql : kl;
        #pragma unroll
        for (int i = 0; i < 8; ++i) {
            #pragma unroll
            for (int j = 0; j < 4; ++j) {
                const int col = col0 + wc * 64 + j * 16 + (lane & 15);
                const float b = bias[col];
                #pragma unroll
                for (int r = 0; r < 4; ++r) {
                    const int row = row0 + wr * 128 + i * 16 + (lane >> 4) * 4 + r;
                    const float vv = acc[i][j][r] + b;
                    const f16 hh = (f16)vv;
                    oh[(size_t)row * Ee + col] = hh;
                    ol[(size_t)row * Ee + col] = (f16)(vv - (float)hh);
                }
            }
        }
    } else {
        #pragma unroll
        for (int i = 0; i < 8; ++i) {
            #pragma unroll
            for (int j = 0; j < 4; ++j) {
                const int e = col0 + wc * 64 + j * 16 + (lane & 15);
                const float b = bias[e];
                const int srow = row0 + wr * 128 + i * 16 + (lane >> 4) * 4;
                const int bb = srow >> 11;
                const int s = srow & 2047;
                f16x4 pk;
                #pragma unroll
                for (int r = 0; r < 4; ++r) pk[r] = (f16)(acc[i][j][r] + b);
                *(f16x4*)&vT[((size_t)bb * Ee + e) * Ss + s] = pk;
            }
        }
    }
}

// ================================================================ Kernel C: scores (8-phase)
// grid 64*nb 1D, XCD-swizzled. S = q k^T per batch, 3-pass split, fp32 out.
__global__ __launch_bounds__(512, 2)
void score8(const f16* __restrict__ qh, const f16* __restrict__ ql,
            const f16* __restrict__ kh, const f16* __restrict__ kl,
            float* __restrict__ Sbuf, int batch0)
{
    __shared__ f16 As[32768];
    __shared__ f16 Bs[32768];

    const int lin = blockIdx.x;
    const int cpx = gridDim.x >> 3;
    const int l = (lin & 7) * cpx + (lin >> 3);
    const int bn = l & 7;
    const int bm = (l >> 3) & 7;
    const int zb = l >> 6;
    const int b = batch0 + zb;

    const int t = threadIdx.x;
    const int lane = t & 63;
    const int w = t >> 6;
    const int wr = w >> 2, wc = w & 3;

    const f16* Aq_h = qh + ((size_t)b * Ss + bm * 256) * Ee;
    const f16* Aq_l = ql + ((size_t)b * Ss + bm * 256) * Ee;
    const f16* Bk_h = kh + ((size_t)b * Ss + bn * 256) * Ee;
    const f16* Bk_l = kl + ((size_t)b * Ss + bn * 256) * Ee;

    f32x4v acc[8][4];
    #pragma unroll
    for (int i = 0; i < 8; ++i)
        #pragma unroll
        for (int j = 0; j < 4; ++j) acc[i][j] = (f32x4v)0.f;

    // passes: (qh,kh), (qh,kl), (ql,kh)
    kloop8(Aq_h, Aq_h, Aq_l, Bk_h, Bk_l, Bk_h, 3, As, Bs, acc, w, lane);

    #pragma unroll
    for (int i = 0; i < 8; ++i) {
        #pragma unroll
        for (int j = 0; j < 4; ++j) {
            const int col = bn * 256 + wc * 64 + j * 16 + (lane & 15);
            #pragma unroll
            for (int r = 0; r < 4; ++r) {
                const int row = zb * Ss + bm * 256 + wr * 128 + i * 16 + (lane >> 4) * 4 + r;
                Sbuf[(size_t)row * 2048 + col] = acc[i][j][r];
            }
        }
    }
}

// ================================================================ Kernel D: row softmax
__global__ __launch_bounds__(256)
void softmax_rows(float* __restrict__ Sbuf)
{
    __shared__ float red[8];
    const int t = threadIdx.x;
    const int w = t >> 6;
    float* Srow = Sbuf + (size_t)blockIdx.x * 2048;

    float4 a = *(const float4*)&Srow[t * 8];
    float4 c = *(const float4*)&Srow[t * 8 + 4];
    float v[8] = {a.x, a.y, a.z, a.w, c.x, c.y, c.z, c.w};

    float m = v[0];
    #pragma unroll
    for (int i = 1; i < 8; ++i) m = fmaxf(m, v[i]);
    #pragma unroll
    for (int off = 1; off < 64; off <<= 1) m = fmaxf(m, __shfl_xor(m, off, 64));
    if ((t & 63) == 0) red[w] = m;
    __syncthreads();
    m = fmaxf(fmaxf(red[0], red[1]), fmaxf(red[2], red[3]));

    float e[8], s = 0.f;
    #pragma unroll
    for (int i = 0; i < 8; ++i) { e[i] = __expf(v[i] - m); s += e[i]; }
    #pragma unroll
    for (int off = 1; off < 64; off <<= 1) s += __shfl_xor(s, off, 64);
    if ((t & 63) == 0) red[4 + w] = s;
    __syncthreads();
    s = red[4] + red[5] + red[6] + red[7];

    const float inv = 1.0f / s;
    f16x8 pk;
    #pragma unroll
    for (int i = 0; i < 8; ++i) pk[i] = (f16)(e[i] * inv);
    *(f16x8*)(((f16*)Srow) + t * 8) = pk;
}

// ================================================================ Kernel E: O = P * v (128^2 m97-style)
__global__ __launch_bounds__(256)
void pv_gemm(const float* __restrict__ Sbuf, const f16* __restrict__ vT,
             float* __restrict__ out, int batch0)
{
    __shared__ f16 Pt[128][32];
    __shared__ f16 Vt[128][32];

    const int zb = blockIdx.z;
    const int b = batch0 + zb;
    const int bm = blockIdx.y;
    const int bn = blockIdx.x;

    const int t = threadIdx.x;
    const int lane = t & 63;
    const int w = t >> 6;
    const int wr = w >> 1, wc = w & 1;
    const int lr = lane & 15;
    const int kq = (lane >> 4) << 3;

    const int rS = w * 32 + (lane >> 2);
    const int eS = (lane & 3) * 8;

    const f16* Pbase = (const f16*)Sbuf;
    const f16* gA = Pbase + ((size_t)(zb * Ss + bm * 128 + rS)) * 4096 + eS;
    const f16* gB = vT + ((size_t)b * Ee + bn * 128 + rS) * Ss + eS;

    f32x4v acc[4][4];
    #pragma unroll
    for (int i = 0; i < 4; ++i)
        #pragma unroll
        for (int j = 0; j < 4; ++j) acc[i][j] = (f32x4v)0.f;

    for (int k0 = 0; k0 < Ss; k0 += 32) {
        __syncthreads();
        #pragma unroll
        for (int c = 0; c < 2; ++c) {
            const int lo = w * 1024 + c * 512;
            gll16(gA + (size_t)c * 16 * 4096 + k0, &Pt[0][0] + lo);
            gll16(gB + (size_t)c * 16 * Ss + k0,   &Vt[0][0] + lo);
        }
        __syncthreads();

        f16x8 fa[4], fb[4];
        #pragma unroll
        for (int i = 0; i < 4; ++i) {
            fa[i] = *(const f16x8*)&Pt[wr * 64 + i * 16 + lr][kq];
            fb[i] = *(const f16x8*)&Vt[wc * 64 + i * 16 + lr][kq];
        }
        #pragma unroll
        for (int i = 0; i < 4; ++i)
            #pragma unroll
            for (int j = 0; j < 4; ++j)
                acc[i][j] = MFMA16(fa[i], fb[j], acc[i][j]);
    }

    #pragma unroll
    for (int i = 0; i < 4; ++i) {
        #pragma unroll
        for (int j = 0; j < 4; ++j) {
            const int col = bn * 128 + wc * 64 + j * 16 + lr;
            #pragma unroll
            for (int r = 0; r < 4; ++r) {
                const int row = bm * 128 + wr * 64 + i * 16 + (lane >> 4) * 4 + r;
                out[((size_t)b * Ss + row) * Ee + col] = acc[i][j][r];
            }
        }
    }
}

// ================================================================ legacy path (fp32 fallback)
#define TQ 16
#define TK 256
#define EC 64
#define NCH (Ee/EC)
#define NT  (Ss/TK)

__global__ __launch_bounds__(256)
void qkv_gemm(const float* __restrict__ x,
              const float* __restrict__ Wq, const float* __restrict__ bq,
              const float* __restrict__ Wk, const float* __restrict__ bk,
              const float* __restrict__ Wv, const float* __restrict__ bv,
              float* __restrict__ oq, float* __restrict__ ok, float* __restrict__ ov)
{
    __shared__ float Xs[64][17];
    __shared__ float Ws[64][17];
    const int t = threadIdx.x;
    const int z = blockIdx.z;
    const float* __restrict__ W    = (z == 0) ? Wq : ((z == 1) ? Wk : Wv);
    const float* __restrict__ bias = (z == 0) ? bq : ((z == 1) ? bk : bv);
    float* __restrict__ out        = (z == 0) ? oq : ((z == 1) ? ok : ov);

    const int row0 = blockIdx.y << 6;
    const int col0 = blockIdx.x << 6;
    const int ti = t >> 4;
    const int tj = t & 15;
    const int lr = t >> 2;
    const int lc = (t & 3) << 2;

    float acc[4][4];
    #pragma unroll
    for (int i = 0; i < 4; ++i)
        #pragma unroll
        for (int j = 0; j < 4; ++j) acc[i][j] = 0.f;

    for (int e0 = 0; e0 < Ee; e0 += 16) {
        __syncthreads();
        {
            float4 xv = *(const float4*)&x[(row0 + lr)*Ee + e0 + lc];
            float4 wv = *(const float4*)&W[(col0 + lr)*Ee + e0 + lc];
            Xs[lr][lc]   = xv.x; Xs[lr][lc+1] = xv.y; Xs[lr][lc+2] = xv.z; Xs[lr][lc+3] = xv.w;
            Ws[lr][lc]   = wv.x; Ws[lr][lc+1] = wv.y; Ws[lr][lc+2] = wv.z; Ws[lr][lc+3] = wv.w;
        }
        __syncthreads();
        #pragma unroll
        for (int ee = 0; ee < 16; ++ee) {
            float xa[4], wb[4];
            #pragma unroll
            for (int i = 0; i < 4; ++i) xa[i] = Xs[(ti<<2)+i][ee];
            #pragma unroll
            for (int j = 0; j < 4; ++j) wb[j] = Ws[(tj<<2)+j][ee];
            #pragma unroll
            for (int i = 0; i < 4; ++i)
                #pragma unroll
                for (int j = 0; j < 4; ++j)
                    acc[i][j] = fmaf(xa[i], wb[j], acc[i][j]);
        }
    }

    const float4 b4 = *(const float4*)&bias[col0 + (tj<<2)];
    #pragma unroll
    for (int i = 0; i < 4; ++i) {
        float4 o;
        o.x = acc[i][0] + b4.x;
        o.y = acc[i][1] + b4.y;
        o.z = acc[i][2] + b4.z;
        o.w = acc[i][3] + b4.w;
        *(float4*)&out[(row0 + (ti<<2) + i)*Ee + col0 + (tj<<2)] = o;
    }
}

__global__ __launch_bounds__(256)
void flash_attn(const float* __restrict__ qsrc,
                const float* __restrict__ ksrc,
                const float* __restrict__ vsrc,
                float* __restrict__ out)
{
    __shared__ float qs[TQ][1028];
    __shared__ float kv[TK][68];
    __shared__ float ps[TQ][260];
    __shared__ float f_s[TQ];
    __shared__ float l_s[TQ];

    const int t = threadIdx.x;
    const int lane = t & 63;
    const int w = t >> 6;
    const int q0 = blockIdx.x * TQ;
    const int kb = (q0 / Ss) * Ss;

    {
        const int r = t >> 4;
        const int c0 = (t & 15) << 2;
        #pragma unroll
        for (int m = 0; m < 16; ++m) {
            float4 v4 = *(const float4*)&qsrc[(q0 + r)*Ee + c0 + (m << 6)];
            *(float4*)&qs[r][c0 + (m << 6)] = v4;
        }
    }

    float4 oacc[NCH];
    #pragma unroll
    for (int i = 0; i < NCH; ++i) oacc[i] = make_float4(0.f, 0.f, 0.f, 0.f);
    float m_reg[4], l_reg[4];
    #pragma unroll
    for (int i = 0; i < 4; ++i) { m_reg[i] = -INFINITY; l_reg[i] = 0.f; }

    const int ow = t >> 4;
    const int oc = (t & 15) << 2;

    for (int kt = 0; kt < NT; ++kt) {
        const int kr0 = kb + kt * TK;

        float sacc[4][4];
        #pragma unroll
        for (int i = 0; i < 4; ++i)
            #pragma unroll
            for (int j = 0; j < 4; ++j) sacc[i][j] = 0.f;

        for (int ec = 0; ec < NCH; ++ec) {
            __syncthreads();
            {
                const int rr = t >> 4;
                const int cc = (t & 15) << 2;
                #pragma unroll
                for (int m = 0; m < 16; ++m) {
                    float4 v4 = *(const float4*)&ksrc[(kr0 + rr + (m<<4))*Ee + ec*EC + cc];
                    *(float4*)&kv[rr + (m<<4)][cc] = v4;
                }
            }
            __syncthreads();
            #pragma unroll 4
            for (int ee = 0; ee < EC; ee += 4) {
                float4 q4[4];
                #pragma unroll
                for (int i = 0; i < 4; ++i)
                    q4[i] = *(const float4*)&qs[(w<<2)+i][ec*EC + ee];
                #pragma unroll
                for (int j = 0; j < 4; ++j) {
                    float4 k4 = *(const float4*)&kv[lane + (j<<6)][ee];
                    #pragma unroll
                    for (int i = 0; i < 4; ++i) {
                        sacc[i][j] = fmaf(q4[i].x, k4.x, sacc[i][j]);
                        sacc[i][j] = fmaf(q4[i].y, k4.y, sacc[i][j]);
                        sacc[i][j] = fmaf(q4[i].z, k4.z, sacc[i][j]);
                        sacc[i][j] = fmaf(q4[i].w, k4.w, sacc[i][j]);
                    }
                }
            }
        }

        float tmax[4];
        #pragma unroll
        for (int i = 0; i < 4; ++i)
            tmax[i] = fmaxf(fmaxf(sacc[i][0], sacc[i][1]), fmaxf(sacc[i][2], sacc[i][3]));
        #pragma unroll
        for (int off = 1; off < 64; off <<= 1) {
            #pragma unroll
            for (int i = 0; i < 4; ++i)
                tmax[i] = fmaxf(tmax[i], __shfl_xor(tmax[i], off, 64));
        }
        float rs[4], fi[4];
        #pragma unroll
        for (int i = 0; i < 4; ++i) {
            float mn = fmaxf(m_reg[i], tmax[i]);
            fi[i] = __expf(m_reg[i] - mn);
            m_reg[i] = mn;
            float r = 0.f;
            #pragma unroll
            for (int j = 0; j < 4; ++j) {
                float p = __expf(sacc[i][j] - mn);
                ps[(w<<2)+i][lane + (j<<6)] = p;
                r += p;
            }
            rs[i] = r;
        }
        #pragma unroll
        for (int off = 1; off < 64; off <<= 1) {
            #pragma unroll
            for (int i = 0; i < 4; ++i)
                rs[i] += __shfl_xor(rs[i], off, 64);
        }
        #pragma unroll
        for (int i = 0; i < 4; ++i)
            l_reg[i] = l_reg[i] * fi[i] + rs[i];
        if (lane == 0) {
            #pragma unroll
            for (int i = 0; i < 4; ++i) {
                f_s[(w<<2)+i] = fi[i];
                l_s[(w<<2)+i] = l_reg[i];
            }
        }
        __syncthreads();

        const float fown = f_s[ow];
        #pragma unroll
        for (int c4 = 0; c4 < NCH; ++c4) {
            oacc[c4].x *= fown; oacc[c4].y *= fown;
            oacc[c4].z *= fown; oacc[c4].w *= fown;
        }
        for (int pc = 0; pc < NCH; ++pc) {
            __syncthreads();
            {
                const int rr = t >> 4;
                const int cc = (t & 15) << 2;
                #pragma unroll
                for (int m = 0; m < 16; ++m) {
                    float4 v4 = *(const float4*)&vsrc[(kr0 + rr + (m<<4))*Ee + pc*EC + cc];
                    *(float4*)&kv[rr + (m<<4)][cc] = v4;
                }
            }
            __syncthreads();
            float4 acc = oacc[pc];
            #pragma unroll 4
            for (int tj0 = 0; tj0 < TK; tj0 += 4) {
                float4 p4 = *(const float4*)&ps[ow][tj0];
                float4 v0 = *(const float4*)&kv[tj0+0][oc];
                float4 v1 = *(const float4*)&kv[tj0+1][oc];
                float4 v2 = *(const float4*)&kv[tj0+2][oc];
                float4 v3 = *(const float4*)&kv[tj0+3][oc];
                acc.x = fmaf(p4.x, v0.x, acc.x); acc.y = fmaf(p4.x, v0.y, acc.y);
                acc.z = fmaf(p4.x, v0.z, acc.z); acc.w = fmaf(p4.x, v0.w, acc.w);
                acc.x = fmaf(p4.y, v1.x, acc.x); acc.y = fmaf(p4.y, v1.y, acc.y);
                acc.z = fmaf(p4.y, v1.z, acc.z); acc.w = fmaf(p4.y, v1.w, acc.w);
                acc.x = fmaf(p4.z, v2.x, acc.x); acc.y = fmaf(p4.z, v2.y, acc.y);
                acc.z = fmaf(p4.z, v2.z, acc.z); acc.w = fmaf(p4.z, v2.w, acc.w);
                acc.x = fmaf(p4.w, v3.x, acc.x); acc.y = fmaf(p4.w, v3.y, acc.y);
                acc.z = fmaf(p4.w, v3.z, acc.z); acc.w = fmaf(p4.w, v3.w, acc.w);
            }
            oacc[pc] = acc;
        }
    }

    __syncthreads();
    const float linv = 1.0f / l_s[ow];
    #pragma unroll
    for (int c4 = 0; c4 < NCH; ++c4) {
        float4 o = oacc[c4];
        o.x *= linv; o.y *= linv; o.z *= linv; o.w *= linv;
        *(float4*)&out[(q0 + ow)*Ee + oc + (c4 << 6)] = o;
    }
}

// ================================================================ launch
extern "C" void kernel_launch(void* const* d_in, const int* in_sizes, int n_in,
                              void* d_out, int out_size, void* d_ws, size_t ws_size,
                              hipStream_t stream)
{
    (void)in_sizes; (void)n_in; (void)out_size;
    const float* x  = (const float*)d_in[0];
    const float* Wq = (const float*)d_in[1];
    const float* bq = (const float*)d_in[2];
    const float* Wk = (const float*)d_in[3];
    const float* bk = (const float*)d_in[4];
    const float* Wv = (const float*)d_in[5];
    const float* bv = (const float*)d_in[6];
    float* out = (float*)d_out;

    const size_t WPL  = 2097152ull;       // bytes per W plane
    const size_t QPL  = 33554432ull;      // bytes per q/k plane
    const size_t S4   = 67108864ull;      // Sbuf for 4-batch chunks
    const size_t S2   = 33554432ull;      // Sbuf for 2-batch chunks
    const size_t NEED4 = S4 + 5 * WPL + 4 * QPL + 33554432ull;  // 245366784
    const size_t NEED2 = S2 + 5 * WPL + 4 * QPL + 33554432ull;  // 211812352

    if (ws_size >= NEED2) {
        const int nb = (ws_size >= NEED4) ? 4 : 2;
        const size_t sbytes = (nb == 4) ? S4 : S2;
        float* Sbuf = (float*)d_ws;
        f16* Wqh = (f16*)((char*)d_ws + sbytes);
        f16* Wql = Wqh + 1048576;
        f16* Wkh = Wqh + 2 * 1048576;
        f16* Wkl = Wqh + 3 * 1048576;
        f16* Wvh = Wqh + 4 * 1048576;
        f16* qh = (f16*)((char*)d_ws + sbytes + 5 * WPL);
        f16* ql = qh + 16777216;
        f16* kh = qh + 2 * 16777216;
        f16* kl = qh + 3 * 16777216;
        f16* vT = (f16*)((char*)d_ws + sbytes + 5 * WPL + 4 * QPL);
        f16* xh = (f16*)d_out;                 // 32 MB scratch (overwritten by pv)
        f16* xl = xh + (size_t)BSr * Ee;       // 32 MB

        split_weights<<<1024, 256, 0, stream>>>(Wq, Wk, Wv, Wqh, Wql, Wkh, Wkl, Wvh);
        split_x<<<16384, 256, 0, stream>>>(x, xh, xl);
        proj8<<<768, 512, 0, stream>>>(
            xh, xl, Wqh, Wql, Wkh, Wkl, Wvh, bq, bk, bv, qh, ql, kh, kl, vT);
        for (int c = 0; c < 8 / nb; ++c) {
            score8<<<64 * nb, 512, 0, stream>>>(qh, ql, kh, kl, Sbuf, nb * c);
            softmax_rows<<<nb * 2048, 256, 0, stream>>>(Sbuf);
            pv_gemm<<<dim3(8, 16, nb), 256, 0, stream>>>(Sbuf, vT, out, nb * c);
        }
    } else {
        // legacy fp32 path (needs 128 MB ws)
        float* kbuf = (float*)d_ws;
        float* vbuf = kbuf + (size_t)BSr * Ee;
        dim3 g1(Ee / 64, BSr / 64, 3);
        qkv_gemm<<<g1, 256, 0, stream>>>(x, Wq, bq, Wk, bk, Wv, bv, out, kbuf, vbuf);
        flash_attn<<<dim3(BSr / TQ), 256, 0, stream>>>(out, kbuf, vbuf, out);
    }
}

// Round 7
// 467.597 us; speedup vs baseline: 1.6346x; 1.6346x over previous
//
#include <hip/hip_runtime.h>
#include <math.h>

typedef _Float16 f16;
typedef _Float16 f16x8 __attribute__((ext_vector_type(8)));
typedef _Float16 f16x4 __attribute__((ext_vector_type(4)));
typedef float f32x4v __attribute__((ext_vector_type(4)));

#define Bb 8
#define Ss 2048
#define Ee 1024
#define BSr (Bb*Ss)

// ---------------------------------------------------------------- helpers
__device__ __forceinline__ void gll16(const void* gp, void* lp) {
    __builtin_amdgcn_global_load_lds(
        (const __attribute__((address_space(1))) unsigned int*)gp,
        (__attribute__((address_space(3))) unsigned int*)lp,
        16, 0, 0);
}

#define MFMA16(a, b, c) __builtin_amdgcn_mfma_f32_16x16x32_f16((a), (b), (c), 0, 0, 0)
#define SBAR() asm volatile("s_barrier" ::: "memory")
#define WAIT_LGKM0() do { asm volatile("s_waitcnt lgkmcnt(0)" ::: "memory"); __builtin_amdgcn_sched_barrier(0); } while (0)

// ================================================================ split kernels
__global__ __launch_bounds__(256)
void split_weights(const float* __restrict__ Wq, const float* __restrict__ Wk,
                   const float* __restrict__ Wv,
                   f16* __restrict__ Wqh, f16* __restrict__ Wql,
                   f16* __restrict__ Wkh, f16* __restrict__ Wkl,
                   f16* __restrict__ Wvh)
{
    const int i = (blockIdx.x * 256 + threadIdx.x) * 4;
    float4 q = *(const float4*)&Wq[i];
    float4 k = *(const float4*)&Wk[i];
    float4 v = *(const float4*)&Wv[i];
    f16x4 qh4, ql4, kh4, kl4, vh4;
#define SPL(val, h4, l4, idx) { f16 hh = (f16)(val); h4[idx] = hh; l4[idx] = (f16)((val) - (float)hh); }
    SPL(q.x, qh4, ql4, 0) SPL(q.y, qh4, ql4, 1) SPL(q.z, qh4, ql4, 2) SPL(q.w, qh4, ql4, 3)
    SPL(k.x, kh4, kl4, 0) SPL(k.y, kh4, kl4, 1) SPL(k.z, kh4, kl4, 2) SPL(k.w, kh4, kl4, 3)
#undef SPL
    vh4[0] = (f16)v.x; vh4[1] = (f16)v.y; vh4[2] = (f16)v.z; vh4[3] = (f16)v.w;
    *(f16x4*)&Wqh[i] = qh4; *(f16x4*)&Wql[i] = ql4;
    *(f16x4*)&Wkh[i] = kh4; *(f16x4*)&Wkl[i] = kl4;
    *(f16x4*)&Wvh[i] = vh4;
}

// x -> fp16 hi plane only (low part's contribution is below noise floor)
__global__ __launch_bounds__(256)
void split_x(const float* __restrict__ x, f16* __restrict__ xh)
{
    const int i = (blockIdx.x * 256 + threadIdx.x) * 4;
    float4 v = *(const float4*)&x[i];
    f16x4 h4;
    h4[0] = (f16)v.x; h4[1] = (f16)v.y; h4[2] = (f16)v.z; h4[3] = (f16)v.w;
    *(f16x4*)&xh[i] = h4;
}

// ================================================================ 8-phase 256x256 K-loop core
// Round-5 staging schedule (measured best): 2 glls per phase, vmcnt(4) at
// end-ph1 (curr ks1 ready) and end-ph3 (next ks0 ready); vmcnt(0) last tile.
__device__ __forceinline__ void kloop8(
    const f16* Ap0, const f16* Ap1, const f16* Ap2,
    const f16* Bp0, const f16* Bp1, const f16* Bp2,
    const int npass, f16* As, f16* Bs,
    f32x4v acc[8][4], const int w, const int lane)
{
    const int wr = w >> 2, wc = w & 3;
    const int srcoff = (w * 16 + (lane & 15)) * Ee + (lane >> 4) * 8;
    const int lread = lane * 8;
    const int nvt = npass << 4;

    {
        const f16* gA = Ap0 + srcoff;
        const f16* gB = Bp0 + srcoff;
        f16* lA = As + w * 512;
        f16* lB = Bs + w * 512;
        gll16(gA,                       lA);
        gll16(gA + (size_t)8 * 16 * Ee, lA + 8 * 512);
        gll16(gA + 32,                  lA + 16 * 512);
        gll16(gA + 32 + (size_t)8 * 16 * Ee, lA + 24 * 512);
        gll16(gB,                       lB);
        gll16(gB + (size_t)8 * 16 * Ee, lB + 8 * 512);
        gll16(gB + 32,                  lB + 16 * 512);
        gll16(gB + 32 + (size_t)8 * 16 * Ee, lB + 24 * 512);
    }
    asm volatile("s_waitcnt vmcnt(0)" ::: "memory");
    SBAR();

    for (int vt = 0; vt < nvt; ++vt) {
        const int buf = vt & 1;
        const bool more = (vt + 1 < nvt);
        const int tn = (vt + 1) & 15;
        const int pn = (vt + 1) >> 4;
        const f16* An = (pn == 0) ? Ap0 : ((pn == 1) ? Ap1 : Ap2);
        const f16* Bn = (pn == 0) ? Bp0 : ((pn == 1) ? Bp1 : Bp2);
        const f16* An_g = An + tn * 64 + srcoff;
        const f16* Bn_g = Bn + tn * 64 + srcoff;
        f16* As_wr = As + (buf ^ 1) * 16384 + w * 512;
        f16* Bs_wr = Bs + (buf ^ 1) * 16384 + w * 512;
        const f16* As_rd = As + buf * 16384;
        const f16* Bs_rd = Bs + buf * 16384;

        f16x8 fa[8], fb0, fb1;

        // ---------------- ph0: ks0, N-frags 0,1
        #pragma unroll
        for (int i = 0; i < 8; ++i)
            fa[i] = *(const f16x8*)(As_rd + (wr * 8 + i) * 512 + lread);
        fb0 = *(const f16x8*)(Bs_rd + (wc * 4 + 0) * 512 + lread);
        fb1 = *(const f16x8*)(Bs_rd + (wc * 4 + 1) * 512 + lread);
        if (more) {
            gll16(An_g,                       As_wr);
            gll16(An_g + (size_t)8 * 16 * Ee, As_wr + 8 * 512);
        }
        SBAR();
        WAIT_LGKM0();
        __builtin_amdgcn_s_setprio(1);
        #pragma unroll
        for (int i = 0; i < 8; ++i) {
            acc[i][0] = MFMA16(fa[i], fb0, acc[i][0]);
            acc[i][1] = MFMA16(fa[i], fb1, acc[i][1]);
        }
        __builtin_amdgcn_s_setprio(0);
        SBAR();

        // ---------------- ph1: ks0, N-frags 2,3
        fb0 = *(const f16x8*)(Bs_rd + (wc * 4 + 2) * 512 + lread);
        fb1 = *(const f16x8*)(Bs_rd + (wc * 4 + 3) * 512 + lread);
        if (more) {
            gll16(Bn_g,                       Bs_wr);
            gll16(Bn_g + (size_t)8 * 16 * Ee, Bs_wr + 8 * 512);
        }
        SBAR();
        WAIT_LGKM0();
        __builtin_amdgcn_s_setprio(1);
        #pragma unroll
        for (int i = 0; i < 8; ++i) {
            acc[i][2] = MFMA16(fa[i], fb0, acc[i][2]);
            acc[i][3] = MFMA16(fa[i], fb1, acc[i][3]);
        }
        __builtin_amdgcn_s_setprio(0);
        if (more) asm volatile("s_waitcnt vmcnt(4)" ::: "memory");
        else      asm volatile("s_waitcnt vmcnt(0)" ::: "memory");
        SBAR();

        // ---------------- ph2: ks1, N-frags 0,1
        #pragma unroll
        for (int i = 0; i < 8; ++i)
            fa[i] = *(const f16x8*)(As_rd + (16 + wr * 8 + i) * 512 + lread);
        fb0 = *(const f16x8*)(Bs_rd + (16 + wc * 4 + 0) * 512 + lread);
        fb1 = *(const f16x8*)(Bs_rd + (16 + wc * 4 + 1) * 512 + lread);
        if (more) {
            gll16(An_g + 32,                       As_wr + 16 * 512);
            gll16(An_g + 32 + (size_t)8 * 16 * Ee, As_wr + 24 * 512);
        }
        SBAR();
        WAIT_LGKM0();
        __builtin_amdgcn_s_setprio(1);
        #pragma unroll
        for (int i = 0; i < 8; ++i) {
            acc[i][0] = MFMA16(fa[i], fb0, acc[i][0]);
            acc[i][1] = MFMA16(fa[i], fb1, acc[i][1]);
        }
        __builtin_amdgcn_s_setprio(0);
        SBAR();

        // ---------------- ph3: ks1, N-frags 2,3
        fb0 = *(const f16x8*)(Bs_rd + (16 + wc * 4 + 2) * 512 + lread);
        fb1 = *(const f16x8*)(Bs_rd + (16 + wc * 4 + 3) * 512 + lread);
        if (more) {
            gll16(Bn_g + 32,                       Bs_wr + 16 * 512);
            gll16(Bn_g + 32 + (size_t)8 * 16 * Ee, Bs_wr + 24 * 512);
        }
        SBAR();
        WAIT_LGKM0();
        __builtin_amdgcn_s_setprio(1);
        #pragma unroll
        for (int i = 0; i < 8; ++i) {
            acc[i][2] = MFMA16(fa[i], fb0, acc[i][2]);
            acc[i][3] = MFMA16(fa[i], fb1, acc[i][3]);
        }
        __builtin_amdgcn_s_setprio(0);
        if (more) asm volatile("s_waitcnt vmcnt(4)" ::: "memory");
        SBAR();
    }
}

// ================================================================ Kernel B: projection (8-phase)
// z=0: q = xh*(Wqh+Wql) 2 passes -> fp16 qh. z=1: k same. z=2: v 1 pass -> vT.
__global__ __launch_bounds__(512, 2)
void proj8(const f16* __restrict__ xh,
           const f16* __restrict__ Wqh, const f16* __restrict__ Wql,
           const f16* __restrict__ Wkh, const f16* __restrict__ Wkl,
           const f16* __restrict__ Wvh,
           const float* __restrict__ bq, const float* __restrict__ bk,
           const float* __restrict__ bv,
           f16* __restrict__ qh, f16* __restrict__ kh,
           f16* __restrict__ vT)
{
    __shared__ f16 As[32768];
    __shared__ f16 Bs[32768];

    const int lin = blockIdx.x;
    const int l = (lin & 7) * 96 + (lin >> 3);
    const int bx12 = l % 12;
    const int by = l / 12;
    const int z = bx12 >> 2;
    const int col0 = (bx12 & 3) * 256;
    const int row0 = by * 256;

    const f16* Wh = (z == 0) ? Wqh : ((z == 1) ? Wkh : Wvh);
    const f16* Wl = (z == 0) ? Wql : ((z == 1) ? Wkl : Wvh);
    const float* bias = (z == 0) ? bq : ((z == 1) ? bk : bv);
    const int npass = (z == 2) ? 1 : 2;

    const int t = threadIdx.x;
    const int lane = t & 63;
    const int w = t >> 6;
    const int wr = w >> 2, wc = w & 3;

    const f16* Ax = xh + (size_t)row0 * Ee;
    const f16* Bwh = Wh + (size_t)col0 * Ee;
    const f16* Bwl = Wl + (size_t)col0 * Ee;

    f32x4v acc[8][4];
    #pragma unroll
    for (int i = 0; i < 8; ++i)
        #pragma unroll
        for (int j = 0; j < 4; ++j) acc[i][j] = (f32x4v)0.f;

    // passes: (xh,Wh), (xh,Wl)   [z==2: (xh,Wvh) only]
    kloop8(Ax, Ax, Ax, Bwh, Bwl, Bwh, npass, As, Bs, acc, w, lane);

    if (z < 2) {
        f16* __restrict__ oh = (z == 0) ? qh : kh;
        #pragma unroll
        for (int i = 0; i < 8; ++i) {
            #pragma unroll
            for (int j = 0; j < 4; ++j) {
                const int col = col0 + wc * 64 + j * 16 + (lane & 15);
                const float b = bias[col];
                #pragma unroll
                for (int r = 0; r < 4; ++r) {
                    const int row = row0 + wr * 128 + i * 16 + (lane >> 4) * 4 + r;
                    oh[(size_t)row * Ee + col] = (f16)(acc[i][j][r] + b);
                }
            }
        }
    } else {
        #pragma unroll
        for (int i = 0; i < 8; ++i) {
            #pragma unroll
            for (int j = 0; j < 4; ++j) {
                const int e = col0 + wc * 64 + j * 16 + (lane & 15);
                const float b = bias[e];
                const int srow = row0 + wr * 128 + i * 16 + (lane >> 4) * 4;
                const int bb = srow >> 11;
                const int s = srow & 2047;
                f16x4 pk;
                #pragma unroll
                for (int r = 0; r < 4; ++r) pk[r] = (f16)(acc[i][j][r] + b);
                *(f16x4*)&vT[((size_t)bb * Ee + e) * Ss + s] = pk;
            }
        }
    }
}

// ================================================================ Kernel C: scores (8-phase, 1 pass)
__global__ __launch_bounds__(512, 2)
void score8(const f16* __restrict__ qh, const f16* __restrict__ kh,
            float* __restrict__ Sbuf, int batch0)
{
    __shared__ f16 As[32768];
    __shared__ f16 Bs[32768];

    const int lin = blockIdx.x;
    const int cpx = gridDim.x >> 3;
    const int l = (lin & 7) * cpx + (lin >> 3);
    const int bn = l & 7;
    const int bm = (l >> 3) & 7;
    const int zb = l >> 6;
    const int b = batch0 + zb;

    const int t = threadIdx.x;
    const int lane = t & 63;
    const int w = t >> 6;
    const int wr = w >> 2, wc = w & 3;

    const f16* Aq = qh + ((size_t)b * Ss + bm * 256) * Ee;
    const f16* Bk = kh + ((size_t)b * Ss + bn * 256) * Ee;

    f32x4v acc[8][4];
    #pragma unroll
    for (int i = 0; i < 8; ++i)
        #pragma unroll
        for (int j = 0; j < 4; ++j) acc[i][j] = (f32x4v)0.f;

    kloop8(Aq, Aq, Aq, Bk, Bk, Bk, 1, As, Bs, acc, w, lane);

    #pragma unroll
    for (int i = 0; i < 8; ++i) {
        #pragma unroll
        for (int j = 0; j < 4; ++j) {
            const int col = bn * 256 + wc * 64 + j * 16 + (lane & 15);
            #pragma unroll
            for (int r = 0; r < 4; ++r) {
                const int row = zb * Ss + bm * 256 + wr * 128 + i * 16 + (lane >> 4) * 4 + r;
                Sbuf[(size_t)row * 2048 + col] = acc[i][j][r];
            }
        }
    }
}

// ================================================================ Kernel D: row softmax
__global__ __launch_bounds__(256)
void softmax_rows(float* __restrict__ Sbuf)
{
    __shared__ float red[8];
    const int t = threadIdx.x;
    const int w = t >> 6;
    float* Srow = Sbuf + (size_t)blockIdx.x * 2048;

    float4 a = *(const float4*)&Srow[t * 8];
    float4 c = *(const float4*)&Srow[t * 8 + 4];
    float v[8] = {a.x, a.y, a.z, a.w, c.x, c.y, c.z, c.w};

    float m = v[0];
    #pragma unroll
    for (int i = 1; i < 8; ++i) m = fmaxf(m, v[i]);
    #pragma unroll
    for (int off = 1; off < 64; off <<= 1) m = fmaxf(m, __shfl_xor(m, off, 64));
    if ((t & 63) == 0) red[w] = m;
    __syncthreads();
    m = fmaxf(fmaxf(red[0], red[1]), fmaxf(red[2], red[3]));

    float e[8], s = 0.f;
    #pragma unroll
    for (int i = 0; i < 8; ++i) { e[i] = __expf(v[i] - m); s += e[i]; }
    #pragma unroll
    for (int off = 1; off < 64; off <<= 1) s += __shfl_xor(s, off, 64);
    if ((t & 63) == 0) red[4 + w] = s;
    __syncthreads();
    s = red[4] + red[5] + red[6] + red[7];

    const float inv = 1.0f / s;
    f16x8 pk;
    #pragma unroll
    for (int i = 0; i < 8; ++i) pk[i] = (f16)(e[i] * inv);
    *(f16x8*)(((f16*)Srow) + t * 8) = pk;
}

// ================================================================ Kernel E: O = P * v (128^2 m97-style)
__global__ __launch_bounds__(256)
void pv_gemm(const float* __restrict__ Sbuf, const f16* __restrict__ vT,
             float* __restrict__ out, int batch0)
{
    __shared__ f16 Pt[128][32];
    __shared__ f16 Vt[128][32];

    const int zb = blockIdx.z;
    const int b = batch0 + zb;
    const int bm = blockIdx.y;
    const int bn = blockIdx.x;

    const int t = threadIdx.x;
    const int lane = t & 63;
    const int w = t >> 6;
    const int wr = w >> 1, wc = w & 1;
    const int lr = lane & 15;
    const int kq = (lane >> 4) << 3;

    const int rS = w * 32 + (lane >> 2);
    const int eS = (lane & 3) * 8;

    const f16* Pbase = (const f16*)Sbuf;
    const f16* gA = Pbase + ((size_t)(zb * Ss + bm * 128 + rS)) * 4096 + eS;
    const f16* gB = vT + ((size_t)b * Ee + bn * 128 + rS) * Ss + eS;

    f32x4v acc[4][4];
    #pragma unroll
    for (int i = 0; i < 4; ++i)
        #pragma unroll
        for (int j = 0; j < 4; ++j) acc[i][j] = (f32x4v)0.f;

    for (int k0 = 0; k0 < Ss; k0 += 32) {
        __syncthreads();
        #pragma unroll
        for (int c = 0; c < 2; ++c) {
            const int lo = w * 1024 + c * 512;
            gll16(gA + (size_t)c * 16 * 4096 + k0, &Pt[0][0] + lo);
            gll16(gB + (size_t)c * 16 * Ss + k0,   &Vt[0][0] + lo);
        }
        __syncthreads();

        f16x8 fa[4], fb[4];
        #pragma unroll
        for (int i = 0; i < 4; ++i) {
            fa[i] = *(const f16x8*)&Pt[wr * 64 + i * 16 + lr][kq];
            fb[i] = *(const f16x8*)&Vt[wc * 64 + i * 16 + lr][kq];
        }
        #pragma unroll
        for (int i = 0; i < 4; ++i)
            #pragma unroll
            for (int j = 0; j < 4; ++j)
                acc[i][j] = MFMA16(fa[i], fb[j], acc[i][j]);
    }

    #pragma unroll
    for (int i = 0; i < 4; ++i) {
        #pragma unroll
        for (int j = 0; j < 4; ++j) {
            const int col = bn * 128 + wc * 64 + j * 16 + lr;
            #pragma unroll
            for (int r = 0; r < 4; ++r) {
                const int row = bm * 128 + wr * 64 + i * 16 + (lane >> 4) * 4 + r;
                out[((size_t)b * Ss + row) * Ee + col] = acc[i][j][r];
            }
        }
    }
}

// ================================================================ legacy path (fp32 fallback)
#define TQ 16
#define TK 256
#define EC 64
#define NCH (Ee/EC)
#define NT  (Ss/TK)

__global__ __launch_bounds__(256)
void qkv_gemm(const float* __restrict__ x,
              const float* __restrict__ Wq, const float* __restrict__ bq,
              const float* __restrict__ Wk, const float* __restrict__ bk,
              const float* __restrict__ Wv, const float* __restrict__ bv,
              float* __restrict__ oq, float* __restrict__ ok, float* __restrict__ ov)
{
    __shared__ float Xs[64][17];
    __shared__ float Ws[64][17];
    const int t = threadIdx.x;
    const int z = blockIdx.z;
    const float* __restrict__ W    = (z == 0) ? Wq : ((z == 1) ? Wk : Wv);
    const float* __restrict__ bias = (z == 0) ? bq : ((z == 1) ? bk : bv);
    float* __restrict__ out        = (z == 0) ? oq : ((z == 1) ? ok : ov);

    const int row0 = blockIdx.y << 6;
    const int col0 = blockIdx.x << 6;
    const int ti = t >> 4;
    const int tj = t & 15;
    const int lr = t >> 2;
    const int lc = (t & 3) << 2;

    float acc[4][4];
    #pragma unroll
    for (int i = 0; i < 4; ++i)
        #pragma unroll
        for (int j = 0; j < 4; ++j) acc[i][j] = 0.f;

    for (int e0 = 0; e0 < Ee; e0 += 16) {
        __syncthreads();
        {
            float4 xv = *(const float4*)&x[(row0 + lr)*Ee + e0 + lc];
            float4 wv = *(const float4*)&W[(col0 + lr)*Ee + e0 + lc];
            Xs[lr][lc]   = xv.x; Xs[lr][lc+1] = xv.y; Xs[lr][lc+2] = xv.z; Xs[lr][lc+3] = xv.w;
            Ws[lr][lc]   = wv.x; Ws[lr][lc+1] = wv.y; Ws[lr][lc+2] = wv.z; Ws[lr][lc+3] = wv.w;
        }
        __syncthreads();
        #pragma unroll
        for (int ee = 0; ee < 16; ++ee) {
            float xa[4], wb[4];
            #pragma unroll
            for (int i = 0; i < 4; ++i) xa[i] = Xs[(ti<<2)+i][ee];
            #pragma unroll
            for (int j = 0; j < 4; ++j) wb[j] = Ws[(tj<<2)+j][ee];
            #pragma unroll
            for (int i = 0; i < 4; ++i)
                #pragma unroll
                for (int j = 0; j < 4; ++j)
                    acc[i][j] = fmaf(xa[i], wb[j], acc[i][j]);
        }
    }

    const float4 b4 = *(const float4*)&bias[col0 + (tj<<2)];
    #pragma unroll
    for (int i = 0; i < 4; ++i) {
        float4 o;
        o.x = acc[i][0] + b4.x;
        o.y = acc[i][1] + b4.y;
        o.z = acc[i][2] + b4.z;
        o.w = acc[i][3] + b4.w;
        *(float4*)&out[(row0 + (ti<<2) + i)*Ee + col0 + (tj<<2)] = o;
    }
}

__global__ __launch_bounds__(256)
void flash_attn(const float* __restrict__ qsrc,
                const float* __restrict__ ksrc,
                const float* __restrict__ vsrc,
                float* __restrict__ out)
{
    __shared__ float qs[TQ][1028];
    __shared__ float kv[TK][68];
    __shared__ float ps[TQ][260];
    __shared__ float f_s[TQ];
    __shared__ float l_s[TQ];

    const int t = threadIdx.x;
    const int lane = t & 63;
    const int w = t >> 6;
    const int q0 = blockIdx.x * TQ;
    const int kb = (q0 / Ss) * Ss;

    {
        const int r = t >> 4;
        const int c0 = (t & 15) << 2;
        #pragma unroll
        for (int m = 0; m < 16; ++m) {
            float4 v4 = *(const float4*)&qsrc[(q0 + r)*Ee + c0 + (m << 6)];
            *(float4*)&qs[r][c0 + (m << 6)] = v4;
        }
    }

    float4 oacc[NCH];
    #pragma unroll
    for (int i = 0; i < NCH; ++i) oacc[i] = make_float4(0.f, 0.f, 0.f, 0.f);
    float m_reg[4], l_reg[4];
    #pragma unroll
    for (int i = 0; i < 4; ++i) { m_reg[i] = -INFINITY; l_reg[i] = 0.f; }

    const int ow = t >> 4;
    const int oc = (t & 15) << 2;

    for (int kt = 0; kt < NT; ++kt) {
        const int kr0 = kb + kt * TK;

        float sacc[4][4];
        #pragma unroll
        for (int i = 0; i < 4; ++i)
            #pragma unroll
            for (int j = 0; j < 4; ++j) sacc[i][j] = 0.f;

        for (int ec = 0; ec < NCH; ++ec) {
            __syncthreads();
            {
                const int rr = t >> 4;
                const int cc = (t & 15) << 2;
                #pragma unroll
                for (int m = 0; m < 16; ++m) {
                    float4 v4 = *(const float4*)&ksrc[(kr0 + rr + (m<<4))*Ee + ec*EC + cc];
                    *(float4*)&kv[rr + (m<<4)][cc] = v4;
                }
            }
            __syncthreads();
            #pragma unroll 4
            for (int ee = 0; ee < EC; ee += 4) {
                float4 q4[4];
                #pragma unroll
                for (int i = 0; i < 4; ++i)
                    q4[i] = *(const float4*)&qs[(w<<2)+i][ec*EC + ee];
                #pragma unroll
                for (int j = 0; j < 4; ++j) {
                    float4 k4 = *(const float4*)&kv[lane + (j<<6)][ee];
                    #pragma unroll
                    for (int i = 0; i < 4; ++i) {
                        sacc[i][j] = fmaf(q4[i].x, k4.x, sacc[i][j]);
                        sacc[i][j] = fmaf(q4[i].y, k4.y, sacc[i][j]);
                        sacc[i][j] = fmaf(q4[i].z, k4.z, sacc[i][j]);
                        sacc[i][j] = fmaf(q4[i].w, k4.w, sacc[i][j]);
                    }
                }
            }
        }

        float tmax[4];
        #pragma unroll
        for (int i = 0; i < 4; ++i)
            tmax[i] = fmaxf(fmaxf(sacc[i][0], sacc[i][1]), fmaxf(sacc[i][2], sacc[i][3]));
        #pragma unroll
        for (int off = 1; off < 64; off <<= 1) {
            #pragma unroll
            for (int i = 0; i < 4; ++i)
                tmax[i] = fmaxf(tmax[i], __shfl_xor(tmax[i], off, 64));
        }
        float rs[4], fi[4];
        #pragma unroll
        for (int i = 0; i < 4; ++i) {
            float mn = fmaxf(m_reg[i], tmax[i]);
            fi[i] = __expf(m_reg[i] - mn);
            m_reg[i] = mn;
            float r = 0.f;
            #pragma unroll
            for (int j = 0; j < 4; ++j) {
                float p = __expf(sacc[i][j] - mn);
                ps[(w<<2)+i][lane + (j<<6)] = p;
                r += p;
            }
            rs[i] = r;
        }
        #pragma unroll
        for (int off = 1; off < 64; off <<= 1) {
            #pragma unroll
            for (int i = 0; i < 4; ++i)
                rs[i] += __shfl_xor(rs[i], off, 64);
        }
        #pragma unroll
        for (int i = 0; i < 4; ++i)
            l_reg[i] = l_reg[i] * fi[i] + rs[i];
        if (lane == 0) {
            #pragma unroll
            for (int i = 0; i < 4; ++i) {
                f_s[(w<<2)+i] = fi[i];
                l_s[(w<<2)+i] = l_reg[i];
            }
        }
        __syncthreads();

        const float fown = f_s[ow];
        #pragma unroll
        for (int c4 = 0; c4 < NCH; ++c4) {
            oacc[c4].x *= fown; oacc[c4].y *= fown;
            oacc[c4].z *= fown; oacc[c4].w *= fown;
        }
        for (int pc = 0; pc < NCH; ++pc) {
            __syncthreads();
            {
                const int rr = t >> 4;
                const int cc = (t & 15) << 2;
                #pragma unroll
                for (int m = 0; m < 16; ++m) {
                    float4 v4 = *(const float4*)&vsrc[(kr0 + rr + (m<<4))*Ee + pc*EC + cc];
                    *(float4*)&kv[rr + (m<<4)][cc] = v4;
                }
            }
            __syncthreads();
            float4 acc = oacc[pc];
            #pragma unroll 4
            for (int tj0 = 0; tj0 < TK; tj0 += 4) {
                float4 p4 = *(const float4*)&ps[ow][tj0];
                float4 v0 = *(const float4*)&kv[tj0+0][oc];
                float4 v1 = *(const float4*)&kv[tj0+1][oc];
                float4 v2 = *(const float4*)&kv[tj0+2][oc];
                float4 v3 = *(const float4*)&kv[tj0+3][oc];
                acc.x = fmaf(p4.x, v0.x, acc.x); acc.y = fmaf(p4.x, v0.y, acc.y);
                acc.z = fmaf(p4.x, v0.z, acc.z); acc.w = fmaf(p4.x, v0.w, acc.w);
                acc.x = fmaf(p4.y, v1.x, acc.x); acc.y = fmaf(p4.y, v1.y, acc.y);
                acc.z = fmaf(p4.y, v1.z, acc.z); acc.w = fmaf(p4.y, v1.w, acc.w);
                acc.x = fmaf(p4.z, v2.x, acc.x); acc.y = fmaf(p4.z, v2.y, acc.y);
                acc.z = fmaf(p4.z, v2.z, acc.z); acc.w = fmaf(p4.z, v2.w, acc.w);
                acc.x = fmaf(p4.w, v3.x, acc.x); acc.y = fmaf(p4.w, v3.y, acc.y);
                acc.z = fmaf(p4.w, v3.z, acc.z); acc.w = fmaf(p4.w, v3.w, acc.w);
            }
            oacc[pc] = acc;
        }
    }

    __syncthreads();
    const float linv = 1.0f / l_s[ow];
    #pragma unroll
    for (int c4 = 0; c4 < NCH; ++c4) {
        float4 o = oacc[c4];
        o.x *= linv; o.y *= linv; o.z *= linv; o.w *= linv;
        *(float4*)&out[(q0 + ow)*Ee + oc + (c4 << 6)] = o;
    }
}

// ================================================================ launch
extern "C" void kernel_launch(void* const* d_in, const int* in_sizes, int n_in,
                              void* d_out, int out_size, void* d_ws, size_t ws_size,
                              hipStream_t stream)
{
    (void)in_sizes; (void)n_in; (void)out_size;
    const float* x  = (const float*)d_in[0];
    const float* Wq = (const float*)d_in[1];
    const float* bq = (const float*)d_in[2];
    const float* Wk = (const float*)d_in[3];
    const float* bk = (const float*)d_in[4];
    const float* Wv = (const float*)d_in[5];
    const float* bv = (const float*)d_in[6];
    float* out = (float*)d_out;

    const size_t WPL  = 2097152ull;       // bytes per W plane
    const size_t QPL  = 33554432ull;      // bytes per q/k plane (fp16 16384x1024)
    const size_t S4   = 67108864ull;      // Sbuf for 4-batch chunks
    const size_t S2   = 33554432ull;      // Sbuf for 2-batch chunks
    // layout: Sbuf | 5 W planes | qh | kh | vT
    const size_t NEED4 = S4 + 5 * WPL + 2 * QPL + 33554432ull;  // ~178 MB
    const size_t NEED2 = S2 + 5 * WPL + 2 * QPL + 33554432ull;  // ~145 MB

    if (ws_size >= NEED2) {
        const int nb = (ws_size >= NEED4) ? 4 : 2;
        const size_t sbytes = (nb == 4) ? S4 : S2;
        float* Sbuf = (float*)d_ws;
        f16* Wqh = (f16*)((char*)d_ws + sbytes);
        f16* Wql = Wqh + 1048576;
        f16* Wkh = Wqh + 2 * 1048576;
        f16* Wkl = Wqh + 3 * 1048576;
        f16* Wvh = Wqh + 4 * 1048576;
        f16* qh = (f16*)((char*)d_ws + sbytes + 5 * WPL);
        f16* kh = qh + 16777216;
        f16* vT = (f16*)((char*)d_ws + sbytes + 5 * WPL + 2 * QPL);
        f16* xh = (f16*)d_out;                 // 32 MB scratch (overwritten by pv)

        split_weights<<<1024, 256, 0, stream>>>(Wq, Wk, Wv, Wqh, Wql, Wkh, Wkl, Wvh);
        split_x<<<16384, 256, 0, stream>>>(x, xh);
        proj8<<<768, 512, 0, stream>>>(
            xh, Wqh, Wql, Wkh, Wkl, Wvh, bq, bk, bv, qh, kh, vT);
        for (int c = 0; c < 8 / nb; ++c) {
            score8<<<64 * nb, 512, 0, stream>>>(qh, kh, Sbuf, nb * c);
            softmax_rows<<<nb * 2048, 256, 0, stream>>>(Sbuf);
            pv_gemm<<<dim3(8, 16, nb), 256, 0, stream>>>(Sbuf, vT, out, nb * c);
        }
    } else {
        // legacy fp32 path (needs 128 MB ws)
        float* kbuf = (float*)d_ws;
        float* vbuf = kbuf + (size_t)BSr * Ee;
        dim3 g1(Ee / 64, BSr / 64, 3);
        qkv_gemm<<<g1, 256, 0, stream>>>(x, Wq, bq, Wk, bk, Wv, bv, out, kbuf, vbuf);
        flash_attn<<<dim3(BSr / TQ), 256, 0, stream>>>(out, kbuf, vbuf, out);
    }
}

// Round 9
// 435.705 us; speedup vs baseline: 1.7543x; 1.0732x over previous
//
#include <hip/hip_runtime.h>
#include <math.h>

typedef _Float16 f16;
typedef _Float16 f16x8 __attribute__((ext_vector_type(8)));
typedef _Float16 f16x4 __attribute__((ext_vector_type(4)));
typedef float f32x4v __attribute__((ext_vector_type(4)));

#define Bb 8
#define Ss 2048
#define Ee 1024
#define BSr (Bb*Ss)

// ---------------------------------------------------------------- helpers
__device__ __forceinline__ void gll16(const void* gp, void* lp) {
    __builtin_amdgcn_global_load_lds(
        (const __attribute__((address_space(1))) unsigned int*)gp,
        (__attribute__((address_space(3))) unsigned int*)lp,
        16, 0, 0);
}

#define MFMA16(a, b, c) __builtin_amdgcn_mfma_f32_16x16x32_f16((a), (b), (c), 0, 0, 0)
#define SBAR() asm volatile("s_barrier" ::: "memory")

// ================================================================ split kernels
__global__ __launch_bounds__(256)
void split_weights(const float* __restrict__ Wq, const float* __restrict__ Wk,
                   const float* __restrict__ Wv,
                   f16* __restrict__ Wqh, f16* __restrict__ Wql,
                   f16* __restrict__ Wkh, f16* __restrict__ Wkl,
                   f16* __restrict__ Wvh)
{
    const int i = (blockIdx.x * 256 + threadIdx.x) * 4;
    float4 q = *(const float4*)&Wq[i];
    float4 k = *(const float4*)&Wk[i];
    float4 v = *(const float4*)&Wv[i];
    f16x4 qh4, ql4, kh4, kl4, vh4;
#define SPL(val, h4, l4, idx) { f16 hh = (f16)(val); h4[idx] = hh; l4[idx] = (f16)((val) - (float)hh); }
    SPL(q.x, qh4, ql4, 0) SPL(q.y, qh4, ql4, 1) SPL(q.z, qh4, ql4, 2) SPL(q.w, qh4, ql4, 3)
    SPL(k.x, kh4, kl4, 0) SPL(k.y, kh4, kl4, 1) SPL(k.z, kh4, kl4, 2) SPL(k.w, kh4, kl4, 3)
#undef SPL
    vh4[0] = (f16)v.x; vh4[1] = (f16)v.y; vh4[2] = (f16)v.z; vh4[3] = (f16)v.w;
    *(f16x4*)&Wqh[i] = qh4; *(f16x4*)&Wql[i] = ql4;
    *(f16x4*)&Wkh[i] = kh4; *(f16x4*)&Wkl[i] = kl4;
    *(f16x4*)&Wvh[i] = vh4;
}

__global__ __launch_bounds__(256)
void split_x(const float* __restrict__ x, f16* __restrict__ xh)
{
    const int i = (blockIdx.x * 256 + threadIdx.x) * 4;
    float4 v = *(const float4*)&x[i];
    f16x4 h4;
    h4[0] = (f16)v.x; h4[1] = (f16)v.y; h4[2] = (f16)v.z; h4[3] = (f16)v.w;
    *(f16x4*)&xh[i] = h4;
}

// ================================================================ K-loop core, round-9 template
// BM=BN=256, BK=32, 512 thr = 8 waves (2M x 4N; per-wave 128x64 out).
// LDS: 3 buffer sets (triple buffer), fragment-ordered subtiles of 512 f16
// in LANE order: gll lane l writes its 16B at subtile offset l*16 B, and the
// fragment read is the SAME lane order (lrd = lane*8 f16 — round-8 bug was a
// row-major lrd that mismatched the staging permutation). ds_read_b128 is a
// contiguous 1024B wave read -> 0 bank conflicts. Per tile: stage tile t+2
// (depth-2 prefetch), read fa[8]+fb[4] (+fbl[4] if DUAL), MFMA interior
// compiler-scheduled, counted vmcnt (6 or 4, never 0 mid-loop), ONE raw
// s_barrier per tile. DUAL fuses the two W-planes into one K-pass: A read
// once, used by 2x MFMA.
template<bool DUAL>
__device__ __forceinline__ void kloop32(
    const f16* __restrict__ Ag, const f16* __restrict__ Bhg,
    const f16* __restrict__ Blg, f16* __restrict__ lds,
    f32x4v acc[8][4], const int w, const int lane)
{
    constexpr int SETF = DUAL ? 24576 : 16384;   // f16 per buffer set
    const int wr = w >> 2, wc = w & 3;
    const int srcoff = (w * 16 + (lane & 15)) * Ee + (lane >> 4) * 8;
    const int lrd = lane * 8;                    // lane-order read (matches gll dest)
    const int NT = 32;

#define STAGE8(t, s) do {                                                   \
        const int k0_ = (t) * 32;                                           \
        const f16* gA_ = Ag + k0_ + srcoff;                                 \
        const f16* gB_ = Bhg + k0_ + srcoff;                                \
        f16* dA_ = lds + (s) * SETF + w * 512;                              \
        f16* dB_ = lds + (s) * SETF + 8192 + w * 512;                       \
        gll16(gA_,                       dA_);                              \
        gll16(gA_ + (size_t)8 * 16 * Ee, dA_ + 8 * 512);                    \
        gll16(gB_,                       dB_);                              \
        gll16(gB_ + (size_t)8 * 16 * Ee, dB_ + 8 * 512);                    \
        if (DUAL) {                                                         \
            const f16* gL_ = Blg + k0_ + srcoff;                            \
            f16* dL_ = lds + (s) * SETF + 16384 + w * 512;                  \
            gll16(gL_,                       dL_);                          \
            gll16(gL_ + (size_t)8 * 16 * Ee, dL_ + 8 * 512);                \
        }                                                                   \
    } while (0)

    STAGE8(0, 0);
    STAGE8(1, 1);
    if (DUAL) asm volatile("s_waitcnt vmcnt(6)" ::: "memory");
    else      asm volatile("s_waitcnt vmcnt(4)" ::: "memory");
    SBAR();

    for (int t = 0; t < NT; ++t) {
        const int s = t % 3;
        if (t + 2 < NT) STAGE8(t + 2, (t + 2) % 3);

        const f16* As = lds + s * SETF;
        const f16* Bh = As + 8192;
        const f16* Bl = As + 16384;
        f16x8 fa[8], fbh[4], fbl[4];
        #pragma unroll
        for (int i = 0; i < 8; ++i)
            fa[i] = *(const f16x8*)(As + (wr * 8 + i) * 512 + lrd);
        #pragma unroll
        for (int j = 0; j < 4; ++j)
            fbh[j] = *(const f16x8*)(Bh + (wc * 4 + j) * 512 + lrd);
        if (DUAL) {
            #pragma unroll
            for (int j = 0; j < 4; ++j)
                fbl[j] = *(const f16x8*)(Bl + (wc * 4 + j) * 512 + lrd);
        }
        #pragma unroll
        for (int j = 0; j < 4; ++j)
            #pragma unroll
            for (int i = 0; i < 8; ++i) {
                acc[i][j] = MFMA16(fa[i], fbh[j], acc[i][j]);
                if (DUAL)
                    acc[i][j] = MFMA16(fa[i], fbl[j], acc[i][j]);
            }

        if (t + 2 < NT) {
            if (DUAL) asm volatile("s_waitcnt vmcnt(6)" ::: "memory");
            else      asm volatile("s_waitcnt vmcnt(4)" ::: "memory");
        } else if (t + 1 < NT) {
            asm volatile("s_waitcnt vmcnt(0)" ::: "memory");
        }
        SBAR();
    }
#undef STAGE8
}

// ================================================================ Kernel B: projection
// grid 768 = 12 (4 ncol x 3 z) x 64 row-tiles, XCD-swizzled.
// z<2: one fused K-pass (Wh+Wl). z=2: single plane (Wvh) -> vT.
__global__ __launch_bounds__(512, 2)
void proj8(const f16* __restrict__ xh,
           const f16* __restrict__ Wqh, const f16* __restrict__ Wql,
           const f16* __restrict__ Wkh, const f16* __restrict__ Wkl,
           const f16* __restrict__ Wvh,
           const float* __restrict__ bq, const float* __restrict__ bk,
           const float* __restrict__ bv,
           f16* __restrict__ qh, f16* __restrict__ kh,
           f16* __restrict__ vT)
{
    __shared__ f16 lds[73728];   // 144 KB: 3 sets x (A 16K + Bh 16K + Bl 16K)

    const int lin = blockIdx.x;
    const int l = (lin & 7) * 96 + (lin >> 3);
    const int bx12 = l % 12;
    const int by = l / 12;
    const int z = bx12 >> 2;
    const int col0 = (bx12 & 3) * 256;
    const int row0 = by * 256;

    const f16* Wh = (z == 0) ? Wqh : ((z == 1) ? Wkh : Wvh);
    const f16* Wl = (z == 0) ? Wql : ((z == 1) ? Wkl : Wvh);
    const float* bias = (z == 0) ? bq : ((z == 1) ? bk : bv);

    const int t = threadIdx.x;
    const int lane = t & 63;
    const int w = t >> 6;
    const int wr = w >> 2, wc = w & 3;

    const f16* Ax = xh + (size_t)row0 * Ee;
    const f16* Bwh = Wh + (size_t)col0 * Ee;
    const f16* Bwl = Wl + (size_t)col0 * Ee;

    f32x4v acc[8][4];
    #pragma unroll
    for (int i = 0; i < 8; ++i)
        #pragma unroll
        for (int j = 0; j < 4; ++j) acc[i][j] = (f32x4v)0.f;

    if (z < 2) kloop32<true>(Ax, Bwh, Bwl, lds, acc, w, lane);
    else       kloop32<false>(Ax, Bwh, Bwh, lds, acc, w, lane);

    if (z < 2) {
        f16* __restrict__ oh = (z == 0) ? qh : kh;
        #pragma unroll
        for (int i = 0; i < 8; ++i) {
            #pragma unroll
            for (int j = 0; j < 4; ++j) {
                const int col = col0 + wc * 64 + j * 16 + (lane & 15);
                const float b = bias[col];
                #pragma unroll
                for (int r = 0; r < 4; ++r) {
                    const int row = row0 + wr * 128 + i * 16 + (lane >> 4) * 4 + r;
                    oh[(size_t)row * Ee + col] = (f16)(acc[i][j][r] + b);
                }
            }
        }
    } else {
        #pragma unroll
        for (int i = 0; i < 8; ++i) {
            #pragma unroll
            for (int j = 0; j < 4; ++j) {
                const int e = col0 + wc * 64 + j * 16 + (lane & 15);
                const float b = bias[e];
                const int srow = row0 + wr * 128 + i * 16 + (lane >> 4) * 4;
                const int bb = srow >> 11;
                const int s = srow & 2047;
                f16x4 pk;
                #pragma unroll
                for (int r = 0; r < 4; ++r) pk[r] = (f16)(acc[i][j][r] + b);
                *(f16x4*)&vT[((size_t)bb * Ee + e) * Ss + s] = pk;
            }
        }
    }
}

// ================================================================ Kernel C: scores (1 pass)
__global__ __launch_bounds__(512, 2)
void score8(const f16* __restrict__ qh, const f16* __restrict__ kh,
            float* __restrict__ Sbuf, int batch0)
{
    __shared__ f16 lds[49152];   // 96 KB: 3 sets x (A 16K + B 16K)

    const int lin = blockIdx.x;
    const int cpx = gridDim.x >> 3;
    const int l = (lin & 7) * cpx + (lin >> 3);
    const int bn = l & 7;
    const int bm = (l >> 3) & 7;
    const int zb = l >> 6;
    const int b = batch0 + zb;

    const int t = threadIdx.x;
    const int lane = t & 63;
    const int w = t >> 6;
    const int wr = w >> 2, wc = w & 3;

    const f16* Aq = qh + ((size_t)b * Ss + bm * 256) * Ee;
    const f16* Bk = kh + ((size_t)b * Ss + bn * 256) * Ee;

    f32x4v acc[8][4];
    #pragma unroll
    for (int i = 0; i < 8; ++i)
        #pragma unroll
        for (int j = 0; j < 4; ++j) acc[i][j] = (f32x4v)0.f;

    kloop32<false>(Aq, Bk, Bk, lds, acc, w, lane);

    #pragma unroll
    for (int i = 0; i < 8; ++i) {
        #pragma unroll
        for (int j = 0; j < 4; ++j) {
            const int col = bn * 256 + wc * 64 + j * 16 + (lane & 15);
            #pragma unroll
            for (int r = 0; r < 4; ++r) {
                const int row = zb * Ss + bm * 256 + wr * 128 + i * 16 + (lane >> 4) * 4 + r;
                Sbuf[(size_t)row * 2048 + col] = acc[i][j][r];
            }
        }
    }
}

// ================================================================ Kernel D: row softmax
__global__ __launch_bounds__(256)
void softmax_rows(float* __restrict__ Sbuf)
{
    __shared__ float red[8];
    const int t = threadIdx.x;
    const int w = t >> 6;
    float* Srow = Sbuf + (size_t)blockIdx.x * 2048;

    float4 a = *(const float4*)&Srow[t * 8];
    float4 c = *(const float4*)&Srow[t * 8 + 4];
    float v[8] = {a.x, a.y, a.z, a.w, c.x, c.y, c.z, c.w};

    float m = v[0];
    #pragma unroll
    for (int i = 1; i < 8; ++i) m = fmaxf(m, v[i]);
    #pragma unroll
    for (int off = 1; off < 64; off <<= 1) m = fmaxf(m, __shfl_xor(m, off, 64));
    if ((t & 63) == 0) red[w] = m;
    __syncthreads();
    m = fmaxf(fmaxf(red[0], red[1]), fmaxf(red[2], red[3]));

    float e[8], s = 0.f;
    #pragma unroll
    for (int i = 0; i < 8; ++i) { e[i] = __expf(v[i] - m); s += e[i]; }
    #pragma unroll
    for (int off = 1; off < 64; off <<= 1) s += __shfl_xor(s, off, 64);
    if ((t & 63) == 0) red[4 + w] = s;
    __syncthreads();
    s = red[4] + red[5] + red[6] + red[7];

    const float inv = 1.0f / s;
    f16x8 pk;
    #pragma unroll
    for (int i = 0; i < 8; ++i) pk[i] = (f16)(e[i] * inv);
    *(f16x8*)(((f16*)Srow) + t * 8) = pk;
}

// ================================================================ Kernel E: O = P * v (128^2 m97-style)
__global__ __launch_bounds__(256)
void pv_gemm(const float* __restrict__ Sbuf, const f16* __restrict__ vT,
             float* __restrict__ out, int batch0)
{
    __shared__ f16 Pt[128][32];
    __shared__ f16 Vt[128][32];

    const int zb = blockIdx.z;
    const int b = batch0 + zb;
    const int bm = blockIdx.y;
    const int bn = blockIdx.x;

    const int t = threadIdx.x;
    const int lane = t & 63;
    const int w = t >> 6;
    const int wr = w >> 1, wc = w & 1;
    const int lr = lane & 15;
    const int kq = (lane >> 4) << 3;

    const int rS = w * 32 + (lane >> 2);
    const int eS = (lane & 3) * 8;

    const f16* Pbase = (const f16*)Sbuf;
    const f16* gA = Pbase + ((size_t)(zb * Ss + bm * 128 + rS)) * 4096 + eS;
    const f16* gB = vT + ((size_t)b * Ee + bn * 128 + rS) * Ss + eS;

    f32x4v acc[4][4];
    #pragma unroll
    for (int i = 0; i < 4; ++i)
        #pragma unroll
        for (int j = 0; j < 4; ++j) acc[i][j] = (f32x4v)0.f;

    for (int k0 = 0; k0 < Ss; k0 += 32) {
        __syncthreads();
        #pragma unroll
        for (int c = 0; c < 2; ++c) {
            const int lo = w * 1024 + c * 512;
            gll16(gA + (size_t)c * 16 * 4096 + k0, &Pt[0][0] + lo);
            gll16(gB + (size_t)c * 16 * Ss + k0,   &Vt[0][0] + lo);
        }
        __syncthreads();

        f16x8 fa[4], fb[4];
        #pragma unroll
        for (int i = 0; i < 4; ++i) {
            fa[i] = *(const f16x8*)&Pt[wr * 64 + i * 16 + lr][kq];
            fb[i] = *(const f16x8*)&Vt[wc * 64 + i * 16 + lr][kq];
        }
        #pragma unroll
        for (int i = 0; i < 4; ++i)
            #pragma unroll
            for (int j = 0; j < 4; ++j)
                acc[i][j] = MFMA16(fa[i], fb[j], acc[i][j]);
    }

    #pragma unroll
    for (int i = 0; i < 4; ++i) {
        #pragma unroll
        for (int j = 0; j < 4; ++j) {
            const int col = bn * 128 + wc * 64 + j * 16 + lr;
            #pragma unroll
            for (int r = 0; r < 4; ++r) {
                const int row = bm * 128 + wr * 64 + i * 16 + (lane >> 4) * 4 + r;
                out[((size_t)b * Ss + row) * Ee + col] = acc[i][j][r];
            }
        }
    }
}

// ================================================================ legacy path (fp32 fallback)
#define TQ 16
#define TK 256
#define EC 64
#define NCH (Ee/EC)
#define NT  (Ss/TK)

__global__ __launch_bounds__(256)
void qkv_gemm(const float* __restrict__ x,
              const float* __restrict__ Wq, const float* __restrict__ bq,
              const float* __restrict__ Wk, const float* __restrict__ bk,
              const float* __restrict__ Wv, const float* __restrict__ bv,
              float* __restrict__ oq, float* __restrict__ ok, float* __restrict__ ov)
{
    __shared__ float Xs[64][17];
    __shared__ float Ws[64][17];
    const int t = threadIdx.x;
    const int z = blockIdx.z;
    const float* __restrict__ W    = (z == 0) ? Wq : ((z == 1) ? Wk : Wv);
    const float* __restrict__ bias = (z == 0) ? bq : ((z == 1) ? bk : bv);
    float* __restrict__ out        = (z == 0) ? oq : ((z == 1) ? ok : ov);

    const int row0 = blockIdx.y << 6;
    const int col0 = blockIdx.x << 6;
    const int ti = t >> 4;
    const int tj = t & 15;
    const int lr = t >> 2;
    const int lc = (t & 3) << 2;

    float acc[4][4];
    #pragma unroll
    for (int i = 0; i < 4; ++i)
        #pragma unroll
        for (int j = 0; j < 4; ++j) acc[i][j] = 0.f;

    for (int e0 = 0; e0 < Ee; e0 += 16) {
        __syncthreads();
        {
            float4 xv = *(const float4*)&x[(row0 + lr)*Ee + e0 + lc];
            float4 wv = *(const float4*)&W[(col0 + lr)*Ee + e0 + lc];
            Xs[lr][lc]   = xv.x; Xs[lr][lc+1] = xv.y; Xs[lr][lc+2] = xv.z; Xs[lr][lc+3] = xv.w;
            Ws[lr][lc]   = wv.x; Ws[lr][lc+1] = wv.y; Ws[lr][lc+2] = wv.z; Ws[lr][lc+3] = wv.w;
        }
        __syncthreads();
        #pragma unroll
        for (int ee = 0; ee < 16; ++ee) {
            float xa[4], wb[4];
            #pragma unroll
            for (int i = 0; i < 4; ++i) xa[i] = Xs[(ti<<2)+i][ee];
            #pragma unroll
            for (int j = 0; j < 4; ++j) wb[j] = Ws[(tj<<2)+j][ee];
            #pragma unroll
            for (int i = 0; i < 4; ++i)
                #pragma unroll
                for (int j = 0; j < 4; ++j)
                    acc[i][j] = fmaf(xa[i], wb[j], acc[i][j]);
        }
    }

    const float4 b4 = *(const float4*)&bias[col0 + (tj<<2)];
    #pragma unroll
    for (int i = 0; i < 4; ++i) {
        float4 o;
        o.x = acc[i][0] + b4.x;
        o.y = acc[i][1] + b4.y;
        o.z = acc[i][2] + b4.z;
        o.w = acc[i][3] + b4.w;
        *(float4*)&out[(row0 + (ti<<2) + i)*Ee + col0 + (tj<<2)] = o;
    }
}

__global__ __launch_bounds__(256)
void flash_attn(const float* __restrict__ qsrc,
                const float* __restrict__ ksrc,
                const float* __restrict__ vsrc,
                float* __restrict__ out)
{
    __shared__ float qs[TQ][1028];
    __shared__ float kv[TK][68];
    __shared__ float ps[TQ][260];
    __shared__ float f_s[TQ];
    __shared__ float l_s[TQ];

    const int t = threadIdx.x;
    const int lane = t & 63;
    const int w = t >> 6;
    const int q0 = blockIdx.x * TQ;
    const int kb = (q0 / Ss) * Ss;

    {
        const int r = t >> 4;
        const int c0 = (t & 15) << 2;
        #pragma unroll
        for (int m = 0; m < 16; ++m) {
            float4 v4 = *(const float4*)&qsrc[(q0 + r)*Ee + c0 + (m << 6)];
            *(float4*)&qs[r][c0 + (m << 6)] = v4;
        }
    }

    float4 oacc[NCH];
    #pragma unroll
    for (int i = 0; i < NCH; ++i) oacc[i] = make_float4(0.f, 0.f, 0.f, 0.f);
    float m_reg[4], l_reg[4];
    #pragma unroll
    for (int i = 0; i < 4; ++i) { m_reg[i] = -INFINITY; l_reg[i] = 0.f; }

    const int ow = t >> 4;
    const int oc = (t & 15) << 2;

    for (int kt = 0; kt < NT; ++kt) {
        const int kr0 = kb + kt * TK;

        float sacc[4][4];
        #pragma unroll
        for (int i = 0; i < 4; ++i)
            #pragma unroll
            for (int j = 0; j < 4; ++j) sacc[i][j] = 0.f;

        for (int ec = 0; ec < NCH; ++ec) {
            __syncthreads();
            {
                const int rr = t >> 4;
                const int cc = (t & 15) << 2;
                #pragma unroll
                for (int m = 0; m < 16; ++m) {
                    float4 v4 = *(const float4*)&ksrc[(kr0 + rr + (m<<4))*Ee + ec*EC + cc];
                    *(float4*)&kv[rr + (m<<4)][cc] = v4;
                }
            }
            __syncthreads();
            #pragma unroll 4
            for (int ee = 0; ee < EC; ee += 4) {
                float4 q4[4];
                #pragma unroll
                for (int i = 0; i < 4; ++i)
                    q4[i] = *(const float4*)&qs[(w<<2)+i][ec*EC + ee];
                #pragma unroll
                for (int j = 0; j < 4; ++j) {
                    float4 k4 = *(const float4*)&kv[lane + (j<<6)][ee];
                    #pragma unroll
                    for (int i = 0; i < 4; ++i) {
                        sacc[i][j] = fmaf(q4[i].x, k4.x, sacc[i][j]);
                        sacc[i][j] = fmaf(q4[i].y, k4.y, sacc[i][j]);
                        sacc[i][j] = fmaf(q4[i].z, k4.z, sacc[i][j]);
                        sacc[i][j] = fmaf(q4[i].w, k4.w, sacc[i][j]);
                    }
                }
            }
        }

        float tmax[4];
        #pragma unroll
        for (int i = 0; i < 4; ++i)
            tmax[i] = fmaxf(fmaxf(sacc[i][0], sacc[i][1]), fmaxf(sacc[i][2], sacc[i][3]));
        #pragma unroll
        for (int off = 1; off < 64; off <<= 1) {
            #pragma unroll
            for (int i = 0; i < 4; ++i)
                tmax[i] = fmaxf(tmax[i], __shfl_xor(tmax[i], off, 64));
        }
        float rs[4], fi[4];
        #pragma unroll
        for (int i = 0; i < 4; ++i) {
            float mn = fmaxf(m_reg[i], tmax[i]);
            fi[i] = __expf(m_reg[i] - mn);
            m_reg[i] = mn;
            float r = 0.f;
            #pragma unroll
            for (int j = 0; j < 4; ++j) {
                float p = __expf(sacc[i][j] - mn);
                ps[(w<<2)+i][lane + (j<<6)] = p;
                r += p;
            }
            rs[i] = r;
        }
        #pragma unroll
        for (int off = 1; off < 64; off <<= 1) {
            #pragma unroll
            for (int i = 0; i < 4; ++i)
                rs[i] += __shfl_xor(rs[i], off, 64);
        }
        #pragma unroll
        for (int i = 0; i < 4; ++i)
            l_reg[i] = l_reg[i] * fi[i] + rs[i];
        if (lane == 0) {
            #pragma unroll
            for (int i = 0; i < 4; ++i) {
                f_s[(w<<2)+i] = fi[i];
                l_s[(w<<2)+i] = l_reg[i];
            }
        }
        __syncthreads();

        const float fown = f_s[ow];
        #pragma unroll
        for (int c4 = 0; c4 < NCH; ++c4) {
            oacc[c4].x *= fown; oacc[c4].y *= fown;
            oacc[c4].z *= fown; oacc[c4].w *= fown;
        }
        for (int pc = 0; pc < NCH; ++pc) {
            __syncthreads();
            {
                const int rr = t >> 4;
                const int cc = (t & 15) << 2;
                #pragma unroll
                for (int m = 0; m < 16; ++m) {
                    float4 v4 = *(const float4*)&vsrc[(kr0 + rr + (m<<4))*Ee + pc*EC + cc];
                    *(float4*)&kv[rr + (m<<4)][cc] = v4;
                }
            }
            __syncthreads();
            float4 acc = oacc[pc];
            #pragma unroll 4
            for (int tj0 = 0; tj0 < TK; tj0 += 4) {
                float4 p4 = *(const float4*)&ps[ow][tj0];
                float4 v0 = *(const float4*)&kv[tj0+0][oc];
                float4 v1 = *(const float4*)&kv[tj0+1][oc];
                float4 v2 = *(const float4*)&kv[tj0+2][oc];
                float4 v3 = *(const float4*)&kv[tj0+3][oc];
                acc.x = fmaf(p4.x, v0.x, acc.x); acc.y = fmaf(p4.x, v0.y, acc.y);
                acc.z = fmaf(p4.x, v0.z, acc.z); acc.w = fmaf(p4.x, v0.w, acc.w);
                acc.x = fmaf(p4.y, v1.x, acc.x); acc.y = fmaf(p4.y, v1.y, acc.y);
                acc.z = fmaf(p4.y, v1.z, acc.z); acc.w = fmaf(p4.y, v1.w, acc.w);
                acc.x = fmaf(p4.z, v2.x, acc.x); acc.y = fmaf(p4.z, v2.y, acc.y);
                acc.z = fmaf(p4.z, v2.z, acc.z); acc.w = fmaf(p4.z, v2.w, acc.w);
                acc.x = fmaf(p4.w, v3.x, acc.x); acc.y = fmaf(p4.w, v3.y, acc.y);
                acc.z = fmaf(p4.w, v3.z, acc.z); acc.w = fmaf(p4.w, v3.w, acc.w);
            }
            oacc[pc] = acc;
        }
    }

    __syncthreads();
    const float linv = 1.0f / l_s[ow];
    #pragma unroll
    for (int c4 = 0; c4 < NCH; ++c4) {
        float4 o = oacc[c4];
        o.x *= linv; o.y *= linv; o.z *= linv; o.w *= linv;
        *(float4*)&out[(q0 + ow)*Ee + oc + (c4 << 6)] = o;
    }
}

// ================================================================ launch
extern "C" void kernel_launch(void* const* d_in, const int* in_sizes, int n_in,
                              void* d_out, int out_size, void* d_ws, size_t ws_size,
                              hipStream_t stream)
{
    (void)in_sizes; (void)n_in; (void)out_size;
    const float* x  = (const float*)d_in[0];
    const float* Wq = (const float*)d_in[1];
    const float* bq = (const float*)d_in[2];
    const float* Wk = (const float*)d_in[3];
    const float* bk = (const float*)d_in[4];
    const float* Wv = (const float*)d_in[5];
    const float* bv = (const float*)d_in[6];
    float* out = (float*)d_out;

    const size_t WPL  = 2097152ull;       // bytes per W plane
    const size_t QPL  = 33554432ull;      // bytes per q/k plane (fp16 16384x1024)
    const size_t S4   = 67108864ull;      // Sbuf for 4-batch chunks
    const size_t S2   = 33554432ull;      // Sbuf for 2-batch chunks
    const size_t NEED4 = S4 + 5 * WPL + 2 * QPL + 33554432ull;  // ~178 MB
    const size_t NEED2 = S2 + 5 * WPL + 2 * QPL + 33554432ull;  // ~145 MB

    if (ws_size >= NEED2) {
        const int nb = (ws_size >= NEED4) ? 4 : 2;
        const size_t sbytes = (nb == 4) ? S4 : S2;
        float* Sbuf = (float*)d_ws;
        f16* Wqh = (f16*)((char*)d_ws + sbytes);
        f16* Wql = Wqh + 1048576;
        f16* Wkh = Wqh + 2 * 1048576;
        f16* Wkl = Wqh + 3 * 1048576;
        f16* Wvh = Wqh + 4 * 1048576;
        f16* qh = (f16*)((char*)d_ws + sbytes + 5 * WPL);
        f16* kh = qh + 16777216;
        f16* vT = (f16*)((char*)d_ws + sbytes + 5 * WPL + 2 * QPL);
        f16* xh = (f16*)d_out;                 // 32 MB scratch (overwritten by pv)

        split_weights<<<1024, 256, 0, stream>>>(Wq, Wk, Wv, Wqh, Wql, Wkh, Wkl, Wvh);
        split_x<<<16384, 256, 0, stream>>>(x, xh);
        proj8<<<768, 512, 0, stream>>>(
            xh, Wqh, Wql, Wkh, Wkl, Wvh, bq, bk, bv, qh, kh, vT);
        for (int c = 0; c < 8 / nb; ++c) {
            score8<<<64 * nb, 512, 0, stream>>>(qh, kh, Sbuf, nb * c);
            softmax_rows<<<nb * 2048, 256, 0, stream>>>(Sbuf);
            pv_gemm<<<dim3(8, 16, nb), 256, 0, stream>>>(Sbuf, vT, out, nb * c);
        }
    } else {
        // legacy fp32 path (needs 128 MB ws)
        float* kbuf = (float*)d_ws;
        float* vbuf = kbuf + (size_t)BSr * Ee;
        dim3 g1(Ee / 64, BSr / 64, 3);
        qkv_gemm<<<g1, 256, 0, stream>>>(x, Wq, bq, Wk, bk, Wv, bv, out, kbuf, vbuf);
        flash_attn<<<dim3(BSr / TQ), 256, 0, stream>>>(out, kbuf, vbuf, out);
    }
}